// Round 6
// baseline (3335.510 us; speedup 1.0000x reference)
//
#include <hip/hip_runtime.h>
#include <hip/hip_cooperative_groups.h>

namespace cg = cooperative_groups;

#define DDIM 80
#define PLANE 6400
#define VOL 512000
#define HALFV 4
#define NVOL 8
#define NTOT (NVOL*VOL)

#define TY 10
#define CZ 10
#define NYT 8           // 80/TY
#define NZC 8           // 80/CZ
#define NCH 20          // float4 chunks per 80-float row
#define RP 84           // padded row floats in E ring
#define ER (TY + 2)     // 12 eroded rows per slice
#define BLK 256
#define CGRID (NVOL*NYT*NZC)   // 512  (needs 2 blocks/CU co-resident)
#define NITER 51

__device__ __forceinline__ float4 f4min(float4 a, float4 b) {
    return make_float4(fminf(a.x,b.x), fminf(a.y,b.y), fminf(a.z,b.z), fminf(a.w,b.w));
}
__device__ __forceinline__ float4 f4max(float4 a, float4 b) {
    return make_float4(fmaxf(a.x,b.x), fmaxf(a.y,b.y), fmaxf(a.z,b.z), fmaxf(a.w,b.w));
}
__device__ __forceinline__ int slot4(int v){ return (v + 8) & 3; }   // v >= -8
__device__ __forceinline__ float updf(float s, float d){ return s + fmaxf(d - s*d, 0.0f); }

struct EIn { float4 c, zA, zB, yA, yB; float lf, rt; };

// ============================ cooperative mega-kernel ============================
// Entire soft_skel (51 iterations) + reduction in ONE kernel. Per iteration:
// 4-slot E ring, one __syncthreads per z-step, depth-1 register prefetch.
// skel tile lives in registers across all 51 iterations.
// __launch_bounds__(256,2): min 2 waves/EU -> VGPR<=256 -> 2 blocks/CU -> 512 co-resident.
__global__ __launch_bounds__(BLK, 2) void mega_k(const float* __restrict__ xin,
                                                 const float* __restrict__ yin,
                                                 float* __restrict__ bufA,
                                                 float* __restrict__ bufB,
                                                 float* __restrict__ partials,
                                                 float* __restrict__ out)
{
    cg::grid_group grid = cg::this_grid();
    __shared__ float E[4][ER][RP];     // 16128 B
    __shared__ float sm[4][2];
    __shared__ float sums[16];

    const int b = blockIdx.x;
    const int v   = b >> 6;            // volume 0..7
    const int rem = b & 63;
    const int yt  = rem >> 3;
    const int zci = rem & 7;
    const int y0 = yt*TY;
    const int z0 = zci*CZ;

    const int tid = threadIdx.x;
    const int r = tid / NCH;           // erode row (valid <12) / dilate row (valid <10)
    const int c = tid - r*NCH;         // chunk 0..19
    const int x4 = 4*c;

    const float* __restrict__ input = (v < HALFV) ? (xin + v*VOL) : (yin + (v-HALFV)*VOL);

    float4 sk[CZ];                     // register-resident skeleton tile (r < TY)

    for (int it = 0; it < NITER; ++it) {
        const float* __restrict__ src = (it == 0) ? input : (((it & 1) ? bufA : bufB) + v*VOL);
        float* __restrict__ ev = ((it & 1) ? bufB : bufA) + v*VOL;
        const bool writeE = (it < NITER-1);
        const bool first  = (it == 0);

        auto loadE = [&](int zs, EIn& e) {
            if (tid < ER*NCH) {
                const int gy  = y0 - 1 + r;
                const int gyc = min(max(gy, 0), DDIM-1);
                const int zcl = min(max(zs, 0), DDIM-1);
                const int zm = max(zcl-1, 0), zp = min(zcl+1, DDIM-1);
                const int ym = max(gyc-1, 0), yp = min(gyc+1, DDIM-1);
                const float* rc = src + zcl*PLANE + gyc*DDIM;
                e.c  = *(const float4*)(rc + x4);
                e.lf = rc[max(x4-1, 0)];
                e.rt = rc[min(x4+4, DDIM-1)];
                e.zA = *(const float4*)(src + zm*PLANE + gyc*DDIM + x4);
                e.zB = *(const float4*)(src + zp*PLANE + gyc*DDIM + x4);
                e.yA = *(const float4*)(src + zcl*PLANE + ym*DDIM + x4);
                e.yB = *(const float4*)(src + zcl*PLANE + yp*DDIM + x4);
            }
        };

        auto erodeStore = [&](int zs, const EIn& e) {
            if (tid < ER*NCH) {
                float4 m;
                m.x = fminf(fminf(e.lf,  e.c.x), e.c.y);
                m.y = fminf(fminf(e.c.x, e.c.y), e.c.z);
                m.z = fminf(fminf(e.c.y, e.c.z), e.c.w);
                m.w = fminf(fminf(e.c.z, e.c.w), e.rt);
                m = f4min(m, f4min(f4min(e.zA, e.zB), f4min(e.yA, e.yB)));
                *(float4*)&E[slot4(zs)][r][x4] = m;
                if (writeE && r >= 1 && r <= TY && zs >= z0 && zs < z0 + CZ)
                    *(float4*)(ev + zs*PLANE + (y0 + r - 1)*DDIM + x4) = m;
            }
        };

        auto loadD = [&](int z, float4& img) {
            if (tid < TY*NCH)
                img = *(const float4*)(src + z*PLANE + (y0 + r)*DDIM + x4);
        };

        EIn eA, eB;
        float4 dA, dB;
        loadE(z0-1, eA);
        loadE(z0,   eB);
        erodeStore(z0-1, eA);
        erodeStore(z0,   eB);
        loadE(z0+1, eA);
        loadD(z0,   dA);
        __syncthreads();

#pragma unroll
        for (int S = 0; S < CZ; ++S) {
            const int z = z0 + S;
            if (S + 1 < CZ) {
                loadE(z + 2, eB);
                loadD(z + 1, dB);
            }
            erodeStore(z + 1, eA);
            __syncthreads();
            if (tid < TY*NCH) {
                const int ty = r;
                const int ss[3] = {slot4(z-1), slot4(z), slot4(z+1)};
                float4 vmax = make_float4(-1e30f, -1e30f, -1e30f, -1e30f);
                float lmax = -1e30f, rmax = -1e30f;
#pragma unroll
                for (int s = 0; s < 3; ++s) {
#pragma unroll
                    for (int l = 0; l < 3; ++l) {
                        const float* row = &E[ss[s]][ty + l][0];
                        const float4 t = *(const float4*)(row + x4);
                        vmax = f4max(vmax, t);
                        lmax = fmaxf(lmax, row[max(x4-1, 0)]);
                        rmax = fmaxf(rmax, row[min(x4+4, DDIM-1)]);
                    }
                }
                float4 dm;
                dm.x = fmaxf(lmax, fmaxf(vmax.x, vmax.y));
                dm.y = fmaxf(vmax.x, fmaxf(vmax.y, vmax.z));
                dm.z = fmaxf(vmax.y, fmaxf(vmax.z, vmax.w));
                dm.w = fmaxf(fmaxf(vmax.z, vmax.w), rmax);

                float4 dl;
                dl.x = fmaxf(dA.x - dm.x, 0.0f);
                dl.y = fmaxf(dA.y - dm.y, 0.0f);
                dl.z = fmaxf(dA.z - dm.z, 0.0f);
                dl.w = fmaxf(dA.w - dm.w, 0.0f);
                if (first) {
                    sk[S] = dl;
                } else {
                    sk[S].x = updf(sk[S].x, dl.x);
                    sk[S].y = updf(sk[S].y, dl.y);
                    sk[S].z = updf(sk[S].z, dl.z);
                    sk[S].w = updf(sk[S].w, dl.w);
                }
            }
            if (S + 1 < CZ) { eA = eB; dA = dB; }
        }

        if (it < NITER-1) grid.sync();
    }

    // fused reduction: register skel x counterpart input
    float sa = 0.0f, sb = 0.0f;
    if (r < TY) {
        const float* __restrict__ cnt =
            (v < HALFV) ? (yin + v*VOL) : (xin + (v-HALFV)*VOL);
#pragma unroll
        for (int S = 0; S < CZ; ++S) {
            const float4 cv = *(const float4*)(cnt + (z0+S)*PLANE + (y0+r)*DDIM + x4);
            sa += cv.x*sk[S].x + cv.y*sk[S].y + cv.z*sk[S].z + cv.w*sk[S].w;
            sb += sk[S].x + sk[S].y + sk[S].z + sk[S].w;
        }
    }
    for (int off = 32; off > 0; off >>= 1) {
        sa += __shfl_down(sa, off);
        sb += __shfl_down(sb, off);
    }
    if ((tid & 63) == 0) { sm[tid >> 6][0] = sa; sm[tid >> 6][1] = sb; }
    __syncthreads();
    if (tid == 0) {
        float a0 = 0, a1 = 0;
        for (int w = 0; w < 4; ++w) { a0 += sm[w][0]; a1 += sm[w][1]; }
        partials[b*2 + 0] = a0;
        partials[b*2 + 1] = a1;
    }
    grid.sync();

    if (b == 0) {
        if (tid < 16) {
            const int vv = tid >> 1, k = tid & 1;
            float acc = 0.0f;
            for (int j = 0; j < 64; ++j) acc += partials[(vv*64 + j)*2 + k];
            sums[tid] = acc;
        }
        __syncthreads();
        if (tid == 0) {
            float acc = 0.0f;
            for (int ch = 0; ch < 4; ++ch) {
                const float tpc     = sums[ch*2 + 0];        // sum clp*y
                const float sum_clp = sums[ch*2 + 1];        // sum clp
                const float tp      = sums[(4+ch)*2 + 0];    // sum x*cll
                const float sum_cll = sums[(4+ch)*2 + 1];    // sum cll
                const float fn  = sum_cll - tp;
                const float fpc = sum_clp - tpc;
                const float clp2voll = (tpc + 1.0f) / (tpc + fpc + 1.0f);
                const float cll2volp = (tp + 1.0f) / (tp + fn + 1.0f);
                acc += 2.0f * clp2voll * cll2volp / (cll2volp + clp2voll + 1e-8f);
            }
            out[0] = 1.0f - acc * 0.25f;
        }
    }
}

// ============================ fallback path (R4, proven) ============================
template<bool FIRST, bool LASTK>
__global__ __launch_bounds__(BLK) void iter_k(const float* __restrict__ xin,
                                              const float* __restrict__ yin,
                                              const float* __restrict__ a,
                                              float* __restrict__ eout,
                                              float* __restrict__ skel)
{
    __shared__ float E[4][ER][RP];

    const int b = blockIdx.x;
    const int v   = b >> 6;
    const int rem = b & 63;
    const int yt  = rem >> 3;
    const int zci = rem & 7;
    const int y0 = yt*TY;
    const int z0 = zci*CZ;

    const float* __restrict__ src =
        FIRST ? ((v < HALFV) ? (xin + v*VOL) : (yin + (v-HALFV)*VOL)) : (a + v*VOL);
    float* __restrict__ ev = LASTK ? nullptr : (eout + v*VOL);
    float* __restrict__ skv = skel + v*VOL;

    const int tid = threadIdx.x;
    const int r = tid / NCH;
    const int c = tid - r*NCH;
    const int x4 = 4*c;

    auto loadE = [&](int zs, EIn& e) {
        if (tid < ER*NCH) {
            const int gy  = y0 - 1 + r;
            const int gyc = min(max(gy, 0), DDIM-1);
            const int zcl = min(max(zs, 0), DDIM-1);
            const int zm = max(zcl-1, 0), zp = min(zcl+1, DDIM-1);
            const int ym = max(gyc-1, 0), yp = min(gyc+1, DDIM-1);
            const float* rc = src + zcl*PLANE + gyc*DDIM;
            e.c  = *(const float4*)(rc + x4);
            e.lf = rc[max(x4-1, 0)];
            e.rt = rc[min(x4+4, DDIM-1)];
            e.zA = *(const float4*)(src + zm*PLANE + gyc*DDIM + x4);
            e.zB = *(const float4*)(src + zp*PLANE + gyc*DDIM + x4);
            e.yA = *(const float4*)(src + zcl*PLANE + ym*DDIM + x4);
            e.yB = *(const float4*)(src + zcl*PLANE + yp*DDIM + x4);
        }
    };
    auto erodeStore = [&](int zs, const EIn& e) {
        if (tid < ER*NCH) {
            float4 m;
            m.x = fminf(fminf(e.lf,  e.c.x), e.c.y);
            m.y = fminf(fminf(e.c.x, e.c.y), e.c.z);
            m.z = fminf(fminf(e.c.y, e.c.z), e.c.w);
            m.w = fminf(fminf(e.c.z, e.c.w), e.rt);
            m = f4min(m, f4min(f4min(e.zA, e.zB), f4min(e.yA, e.yB)));
            *(float4*)&E[slot4(zs)][r][x4] = m;
            if constexpr (!LASTK) {
                if (r >= 1 && r <= TY && zs >= z0 && zs < z0 + CZ)
                    *(float4*)(ev + zs*PLANE + (y0 + r - 1)*DDIM + x4) = m;
            }
        }
    };
    struct DIn { float4 img, sk; };
    auto loadD = [&](int z, DIn& d) {
        if (tid < TY*NCH) {
            const int off = z*PLANE + (y0 + r)*DDIM + x4;
            d.img = *(const float4*)(src + off);
            if constexpr (!FIRST) d.sk = *(const float4*)(skv + off);
        }
    };
    auto dilateUpd = [&](int z, const DIn& d) {
        if (tid < TY*NCH) {
            const int ty = r;
            const int ss[3] = {slot4(z-1), slot4(z), slot4(z+1)};
            float4 vmax = make_float4(-1e30f, -1e30f, -1e30f, -1e30f);
            float lmax = -1e30f, rmax = -1e30f;
#pragma unroll
            for (int s = 0; s < 3; ++s) {
#pragma unroll
                for (int l = 0; l < 3; ++l) {
                    const float* row = &E[ss[s]][ty + l][0];
                    const float4 t = *(const float4*)(row + x4);
                    vmax = f4max(vmax, t);
                    lmax = fmaxf(lmax, row[max(x4-1, 0)]);
                    rmax = fmaxf(rmax, row[min(x4+4, DDIM-1)]);
                }
            }
            float4 dm;
            dm.x = fmaxf(lmax, fmaxf(vmax.x, vmax.y));
            dm.y = fmaxf(vmax.x, fmaxf(vmax.y, vmax.z));
            dm.z = fmaxf(vmax.y, fmaxf(vmax.z, vmax.w));
            dm.w = fmaxf(fmaxf(vmax.z, vmax.w), rmax);
            float4 dl;
            dl.x = fmaxf(d.img.x - dm.x, 0.0f);
            dl.y = fmaxf(d.img.y - dm.y, 0.0f);
            dl.z = fmaxf(d.img.z - dm.z, 0.0f);
            dl.w = fmaxf(d.img.w - dm.w, 0.0f);
            float4 s;
            if constexpr (FIRST) { s = dl; }
            else {
                s = d.sk;
                s.x = updf(s.x, dl.x); s.y = updf(s.y, dl.y);
                s.z = updf(s.z, dl.z); s.w = updf(s.w, dl.w);
            }
            *(float4*)(skv + z*PLANE + (y0+ty)*DDIM + x4) = s;
        }
    };

    EIn eA, eB;
    DIn dA, dB;
    loadE(z0-1, eA);
    loadE(z0,   eB);
    erodeStore(z0-1, eA);
    erodeStore(z0,   eB);
    loadE(z0+1, eA);
    loadD(z0,   dA);
    __syncthreads();
#pragma unroll
    for (int S = 0; S < CZ; ++S) {
        const int z = z0 + S;
        if (S + 1 < CZ) {
            loadE(z + 2, eB);
            loadD(z + 1, dB);
        }
        erodeStore(z + 1, eA);
        __syncthreads();
        dilateUpd(z, dA);
        if (S + 1 < CZ) { eA = eB; dA = dB; }
    }
}

__global__ __launch_bounds__(256) void reduce_k(const float* __restrict__ x,
                                                const float* __restrict__ y,
                                                const float* __restrict__ skel,
                                                float* __restrict__ partials) {
    const int blk = blockIdx.x;
    const int v = blk >> 8;
    const int sub = blk & 255;
    const int base4 = (v * VOL + sub * 2000) >> 2;
    const float4* x4 = (const float4*)x;
    const float4* y4 = (const float4*)y;
    const float4* clp4 = (const float4*)(skel);
    const float4* cll4 = (const float4*)(skel + HALFV * VOL);
    float s1 = 0, s2 = 0, s3 = 0, s4 = 0;
    for (int j = threadIdx.x; j < 500; j += 256) {
        const int i4 = base4 + j;
        const float4 xv = x4[i4];
        const float4 yv = y4[i4];
        const float4 cp = clp4[i4];
        const float4 cl = cll4[i4];
        s1 += xv.x*cl.x + xv.y*cl.y + xv.z*cl.z + xv.w*cl.w;
        s2 += cl.x + cl.y + cl.z + cl.w;
        s3 += cp.x*yv.x + cp.y*yv.y + cp.z*yv.z + cp.w*yv.w;
        s4 += cp.x + cp.y + cp.z + cp.w;
    }
    for (int off = 32; off > 0; off >>= 1) {
        s1 += __shfl_down(s1, off);
        s2 += __shfl_down(s2, off);
        s3 += __shfl_down(s3, off);
        s4 += __shfl_down(s4, off);
    }
    __shared__ float smm[4][4];
    const int wave = threadIdx.x >> 6;
    if ((threadIdx.x & 63) == 0) {
        smm[wave][0] = s1; smm[wave][1] = s2; smm[wave][2] = s3; smm[wave][3] = s4;
    }
    __syncthreads();
    if (threadIdx.x == 0) {
        float a0 = 0, a1 = 0, a2 = 0, a3 = 0;
        for (int w = 0; w < 4; ++w) { a0 += smm[w][0]; a1 += smm[w][1]; a2 += smm[w][2]; a3 += smm[w][3]; }
        partials[blk*4 + 0] = a0;
        partials[blk*4 + 1] = a1;
        partials[blk*4 + 2] = a2;
        partials[blk*4 + 3] = a3;
    }
}

__global__ void final_k(const float* __restrict__ p, float* __restrict__ out) {
    __shared__ float sums[16];
    const int t = threadIdx.x;
    if (t < 16) {
        const int v = t >> 2, k = t & 3;
        float acc = 0.0f;
        for (int b = 0; b < 256; ++b) acc += p[((v << 8) + b)*4 + k];
        sums[t] = acc;
    }
    __syncthreads();
    if (t == 0) {
        float acc = 0.0f;
        for (int v = 0; v < 4; ++v) {
            const float tp      = sums[v*4 + 0];
            const float sum_cll = sums[v*4 + 1];
            const float tpc     = sums[v*4 + 2];
            const float sum_clp = sums[v*4 + 3];
            const float fn  = sum_cll - tp;
            const float fpc = sum_clp - tpc;
            const float clp2voll = (tpc + 1.0f) / (tpc + fpc + 1.0f);
            const float cll2volp = (tp + 1.0f) / (tp + fn + 1.0f);
            acc += 2.0f * clp2voll * cll2volp / (cll2volp + clp2voll + 1e-8f);
        }
        out[0] = 1.0f - acc * 0.25f;
    }
}

extern "C" void kernel_launch(void* const* d_in, const int* in_sizes, int n_in,
                              void* d_out, int out_size, void* d_ws, size_t ws_size,
                              hipStream_t stream) {
    const float* x = (const float*)d_in[0];
    const float* y = (const float*)d_in[1];
    float* out = (float*)d_out;

    float* bufA = (float*)d_ws;
    float* bufB = bufA + NTOT;
    float* skel = bufB + NTOT;
    float* partials = skel + NTOT;   // 4096 floats

    void* args[] = {(void*)&x, (void*)&y, (void*)&bufA, (void*)&bufB,
                    (void*)&partials, (void*)&out};
    hipError_t err = hipLaunchCooperativeKernel(reinterpret_cast<void*>(mega_k),
                                                dim3(CGRID), dim3(BLK), args, 0, stream);
    if (err != hipSuccess) {
        // Fallback: proven R4 multi-kernel path.
        const int GRID = NVOL * NYT * NZC;   // 512
        iter_k<true, false><<<GRID, BLK, 0, stream>>>(x, y, nullptr, bufA, skel);
        for (int t = 1; t <= 49; ++t) {
            iter_k<false, false><<<GRID, BLK, 0, stream>>>(nullptr, nullptr, bufA, bufB, skel);
            float* tmp = bufA; bufA = bufB; bufB = tmp;
        }
        iter_k<false, true><<<GRID, BLK, 0, stream>>>(nullptr, nullptr, bufA, nullptr, skel);
        reduce_k<<<1024, 256, 0, stream>>>(x, y, skel, partials);
        final_k<<<1, 64, 0, stream>>>(partials, out);
    }
}

// Round 7
// 834.003 us; speedup vs baseline: 3.9994x; 3.9994x over previous
//
#include <hip/hip_runtime.h>

#define DDIM 80
#define PLANE 6400
#define VOL 512000
#define HALFV 4
#define NVOL 8
#define NTOT (NVOL*VOL)

#define TY 10
#define CZ 5
#define NYT 8           // 80/TY
#define NZC 16          // 80/CZ
#define NCH 20          // float4 chunks per 80-float row
#define RP 84           // padded row floats in E/H rings
#define ER (TY + 2)     // 12 rows (with y halo)
#define BLK 256
#define GRID (NVOL*NYT*NZC)   // 1024 blocks -> 4/CU -> 16 waves/CU

__device__ __forceinline__ float4 f4min(float4 a, float4 b) {
    return make_float4(fminf(a.x,b.x), fminf(a.y,b.y), fminf(a.z,b.z), fminf(a.w,b.w));
}
__device__ __forceinline__ float4 f4max(float4 a, float4 b) {
    return make_float4(fmaxf(a.x,b.x), fmaxf(a.y,b.y), fmaxf(a.z,b.z), fmaxf(a.w,b.w));
}
__device__ __forceinline__ int slotE(int v){ return (v + 9) % 3; }   // v >= -1
__device__ __forceinline__ int slotH(int v){ return (v + 8) & 3; }   // v >= -1
__device__ __forceinline__ float updf(float s, float d){ return s + fmaxf(d - s*d, 0.0f); }

struct EIn { float4 c, zA, zB, yA, yB; float lf, rt; };

// One skeletonization iteration. Separable dilate:
//   E ring (3 slots): eroded slices (written by erode phase)
//   H ring (4 slots): x-window max of E (written one slice behind erode)
// Dilate(z) = max over 9 aligned f4 from H(z-1,z,z+1) rows ty..ty+2.
// One __syncthreads per z-step; depth-1 register prefetch of all global loads.
template<bool FIRST, bool LASTK>
__global__ __launch_bounds__(BLK, 4) void iter_k(const float* __restrict__ xin,
                                                 const float* __restrict__ yin,
                                                 const float* __restrict__ a,
                                                 float* __restrict__ eout,
                                                 float* __restrict__ skel)
{
    __shared__ float E[3][ER][RP];   // 12096 B
    __shared__ float H[4][ER][RP];   // 16128 B   (total ~27.6 KB)

    const int b = blockIdx.x;
    const int v   = b >> 7;          // volume 0..7
    const int rem = b & 127;
    const int yt  = rem >> 4;        // 0..7
    const int zci = rem & 15;        // 0..15
    const int y0 = yt*TY;
    const int z0 = zci*CZ;

    const float* __restrict__ src =
        FIRST ? ((v < HALFV) ? (xin + v*VOL) : (yin + (v-HALFV)*VOL)) : (a + v*VOL);
    float* __restrict__ ev = LASTK ? nullptr : (eout + v*VOL);
    float* __restrict__ skv = skel + v*VOL;

    const int tid = threadIdx.x;
    const int r = tid / NCH;         // erode/hmax row (valid <12); dilate row (valid <10)
    const int c = tid - r*NCH;       // chunk 0..19
    const int x4 = 4*c;

    // ---- issue the 7+2 global loads for erode of (virtual) slice zs ----
    auto loadE = [&](int zs, EIn& e) {
        if (tid < ER*NCH) {
            const int gy  = y0 - 1 + r;
            const int gyc = min(max(gy, 0), DDIM-1);
            const int zcl = min(max(zs, 0), DDIM-1);
            const int zm = max(zcl-1, 0), zp = min(zcl+1, DDIM-1);
            const int ym = max(gyc-1, 0), yp = min(gyc+1, DDIM-1);
            const float* rc = src + zcl*PLANE + gyc*DDIM;
            e.c  = *(const float4*)(rc + x4);
            e.lf = rc[max(x4-1, 0)];
            e.rt = rc[min(x4+4, DDIM-1)];
            e.zA = *(const float4*)(src + zm*PLANE + gyc*DDIM + x4);
            e.zB = *(const float4*)(src + zp*PLANE + gyc*DDIM + x4);
            e.yA = *(const float4*)(src + zcl*PLANE + ym*DDIM + x4);
            e.yB = *(const float4*)(src + zcl*PLANE + yp*DDIM + x4);
        }
    };

    auto erodeCompute = [&](const EIn& e) -> float4 {
        float4 m;
        m.x = fminf(fminf(e.lf,  e.c.x), e.c.y);
        m.y = fminf(fminf(e.c.x, e.c.y), e.c.z);
        m.z = fminf(fminf(e.c.y, e.c.z), e.c.w);
        m.w = fminf(fminf(e.c.z, e.c.w), e.rt);
        return f4min(m, f4min(f4min(e.zA, e.zB), f4min(e.yA, e.yB)));
    };

    auto storeE = [&](int zs, const float4& m) {
        if (tid < ER*NCH) {
            *(float4*)&E[slotE(zs)][r][x4] = m;
            if constexpr (!LASTK) {
                if (r >= 1 && r <= TY && zs >= z0 && zs < z0 + CZ)
                    *(float4*)(ev + zs*PLANE + (y0 + r - 1)*DDIM + x4) = m;
            }
        }
    };

    // ---- x-window max of eroded slice zs (own chunk in regs, neighbors via LDS) ----
    auto hmaxStore = [&](int zs, const float4& m) {
        if (tid < ER*NCH) {
            const float* er = &E[slotE(zs)][r][0];
            const float lf = (c > 0)  ? er[x4-1] : m.x;
            const float rt = (c < 19) ? er[x4+4] : m.w;
            float4 h;
            h.x = fmaxf(fmaxf(lf,  m.x), m.y);
            h.y = fmaxf(fmaxf(m.x, m.y), m.z);
            h.z = fmaxf(fmaxf(m.y, m.z), m.w);
            h.w = fmaxf(fmaxf(m.z, m.w), rt);
            *(float4*)&H[slotH(zs)][r][x4] = h;
        }
    };

    auto loadD = [&](int z, float4& img, float4& sk) {
        if (tid < TY*NCH) {
            const int off = z*PLANE + (y0 + r)*DDIM + x4;
            img = *(const float4*)(src + off);
            if constexpr (!FIRST) sk = *(const float4*)(skv + off);
        }
    };

    auto dilateUpd = [&](int z, const float4& img, const float4& skin) {
        if (tid < TY*NCH) {
            const int ss[3] = {slotH(z-1), slotH(z), slotH(z+1)};
            float4 dm = make_float4(-1e30f, -1e30f, -1e30f, -1e30f);
#pragma unroll
            for (int s = 0; s < 3; ++s)
#pragma unroll
                for (int l = 0; l < 3; ++l)
                    dm = f4max(dm, *(const float4*)&H[ss[s]][r + l][x4]);

            float4 dl;
            dl.x = fmaxf(img.x - dm.x, 0.0f);
            dl.y = fmaxf(img.y - dm.y, 0.0f);
            dl.z = fmaxf(img.z - dm.z, 0.0f);
            dl.w = fmaxf(img.w - dm.w, 0.0f);
            float4 s;
            if constexpr (FIRST) {
                s = dl;
            } else {
                s = skin;
                s.x = updf(s.x, dl.x); s.y = updf(s.y, dl.y);
                s.z = updf(s.z, dl.z); s.w = updf(s.w, dl.w);
            }
            *(float4*)(skv + z*PLANE + (y0 + r)*DDIM + x4) = s;
        }
    };

    // ---- prologue ----
    EIn eIn, eTmp;
    float4 mOld, mNew;
    float4 dImg, dSk, dImgN, dSkN;

    loadE(z0-1, eIn);
    mOld = erodeCompute(eIn);            // m(z0-1)
    loadE(z0, eTmp);
    mNew = erodeCompute(eTmp);           // m(z0)
    storeE(z0-1, mOld);
    storeE(z0,   mNew);
    loadE(z0+1, eIn);
    __syncthreads();                     // E(z0-1), E(z0) visible
    hmaxStore(z0-1, mOld);               // reads E(z0-1) scalars
    hmaxStore(z0,   mNew);               // reads E(z0)   scalars
    mOld = erodeCompute(eIn);            // m(z0+1); E slot (z0+1)%3 disjoint from read slots
    storeE(z0+1, mOld);
    loadE(z0+2, eIn);                    // for S=0
    loadD(z0, dImg, dSk);
    __syncthreads();                     // H(z0-1), H(z0), E(z0+1) visible

    // ---- main loop: one barrier per z-step ----
#pragma unroll
    for (int S = 0; S < CZ; ++S) {
        const int z = z0 + S;
        // phase A: erode(z+2) from prefetched regs, hmax(z+1) from regs+LDS, prefetch z+3
        if (S <= CZ-3) loadE(z+3, eTmp);
        if (S <= CZ-2) { mNew = erodeCompute(eIn); storeE(z+2, mNew); }
        hmaxStore(z+1, mOld);
        if (S <= CZ-2) loadD(z+1, dImgN, dSkN);
        __syncthreads();
        // phase B: dilate(z) + skeleton update (reads H only)
        dilateUpd(z, dImg, dSk);
        if (S <= CZ-2) { mOld = mNew; dImg = dImgN; dSk = dSkN; }
        if (S <= CZ-3) { eIn = eTmp; }
    }
}

// 1024 blocks: 256 per volume, 2000 contiguous elems each. No atomics.
__global__ __launch_bounds__(256) void reduce_k(const float* __restrict__ x,
                                                const float* __restrict__ y,
                                                const float* __restrict__ skel,
                                                float* __restrict__ partials) {
    const int blk = blockIdx.x;
    const int v = blk >> 8;
    const int sub = blk & 255;
    const int base4 = (v * VOL + sub * 2000) >> 2;
    const float4* x4 = (const float4*)x;
    const float4* y4 = (const float4*)y;
    const float4* clp4 = (const float4*)(skel);
    const float4* cll4 = (const float4*)(skel + HALFV * VOL);
    float s1 = 0, s2 = 0, s3 = 0, s4 = 0;
    for (int j = threadIdx.x; j < 500; j += 256) {
        const int i4 = base4 + j;
        const float4 xv = x4[i4];
        const float4 yv = y4[i4];
        const float4 cp = clp4[i4];
        const float4 cl = cll4[i4];
        s1 += xv.x*cl.x + xv.y*cl.y + xv.z*cl.z + xv.w*cl.w;
        s2 += cl.x + cl.y + cl.z + cl.w;
        s3 += cp.x*yv.x + cp.y*yv.y + cp.z*yv.z + cp.w*yv.w;
        s4 += cp.x + cp.y + cp.z + cp.w;
    }
    for (int off = 32; off > 0; off >>= 1) {
        s1 += __shfl_down(s1, off);
        s2 += __shfl_down(s2, off);
        s3 += __shfl_down(s3, off);
        s4 += __shfl_down(s4, off);
    }
    __shared__ float smm[4][4];
    const int wave = threadIdx.x >> 6;
    if ((threadIdx.x & 63) == 0) {
        smm[wave][0] = s1; smm[wave][1] = s2; smm[wave][2] = s3; smm[wave][3] = s4;
    }
    __syncthreads();
    if (threadIdx.x == 0) {
        float a0 = 0, a1 = 0, a2 = 0, a3 = 0;
        for (int w = 0; w < 4; ++w) { a0 += smm[w][0]; a1 += smm[w][1]; a2 += smm[w][2]; a3 += smm[w][3]; }
        partials[blk*4 + 0] = a0;
        partials[blk*4 + 1] = a1;
        partials[blk*4 + 2] = a2;
        partials[blk*4 + 3] = a3;
    }
}

__global__ void final_k(const float* __restrict__ p, float* __restrict__ out) {
    __shared__ float sums[16];
    const int t = threadIdx.x;
    if (t < 16) {
        const int v = t >> 2, k = t & 3;
        float acc = 0.0f;
        for (int b = 0; b < 256; ++b) acc += p[((v << 8) + b)*4 + k];
        sums[t] = acc;
    }
    __syncthreads();
    if (t == 0) {
        float acc = 0.0f;
        for (int v = 0; v < 4; ++v) {
            const float tp      = sums[v*4 + 0];
            const float sum_cll = sums[v*4 + 1];
            const float tpc     = sums[v*4 + 2];
            const float sum_clp = sums[v*4 + 3];
            const float fn  = sum_cll - tp;
            const float fpc = sum_clp - tpc;
            const float clp2voll = (tpc + 1.0f) / (tpc + fpc + 1.0f);
            const float cll2volp = (tp + 1.0f) / (tp + fn + 1.0f);
            acc += 2.0f * clp2voll * cll2volp / (cll2volp + clp2voll + 1e-8f);
        }
        out[0] = 1.0f - acc * 0.25f;
    }
}

extern "C" void kernel_launch(void* const* d_in, const int* in_sizes, int n_in,
                              void* d_out, int out_size, void* d_ws, size_t ws_size,
                              hipStream_t stream) {
    const float* x = (const float*)d_in[0];
    const float* y = (const float*)d_in[1];
    float* out = (float*)d_out;

    float* bufA = (float*)d_ws;
    float* bufB = bufA + NTOT;
    float* skel = bufB + NTOT;
    float* partials = skel + NTOT;   // 4096 floats

    // iteration 0 (src = inputs, skel init)
    iter_k<true, false><<<GRID, BLK, 0, stream>>>(x, y, nullptr, bufA, skel);
    // iterations 1..49
    for (int t = 1; t <= 49; ++t) {
        iter_k<false, false><<<GRID, BLK, 0, stream>>>(nullptr, nullptr, bufA, bufB, skel);
        float* tmp = bufA; bufA = bufB; bufB = tmp;
    }
    // iteration 50: no e output needed
    iter_k<false, true><<<GRID, BLK, 0, stream>>>(nullptr, nullptr, bufA, nullptr, skel);

    reduce_k<<<1024, 256, 0, stream>>>(x, y, skel, partials);
    final_k<<<1, 64, 0, stream>>>(partials, out);
}